// Round 5
// baseline (293.024 us; speedup 1.0000x reference)
//
#include <hip/hip_runtime.h>
#include <hip/hip_bf16.h>

// FacePartGAT: dense-graph GATConv x2 + mean + fc on MI355X. ALL I/O fp32.
// Key trick: e[i,j] = leaky_relu(t_i + s_j) => softmax aggregation factorizes
// after sorting sources by s_j:
//   out_i = (e^{t_i} SS[k_i] + e^{0.2 t_i} PP[k_i]) / (e^{t_i} zS[k_i] + e^{0.2 t_i} zP[k_i])
// SS/PP suffix/prefix sums over sorted rank, k_i = lower_bound(sortedS, -t_i).
// Exact (reordered summation) — avoids the O(N^2 C) dense aggregation.
// Round 5: fewer+wider dispatches. prep fused (convert+2 transposes); Z sums
// folded into tables as col 128 (width 132, scanz gone); passB fused into
// passC (in-block carry combine); GEMM tiles templated (128x64 / 64x64).

#define NNODE 4096
#define CDIM 128
#define TW 132           // table width: 128 features + z at col 128, pad to 132
#define NEG 0.2f
#define CHUNK 64
#define NCHUNK 64        // NNODE / CHUNK
#define SEG 8
#define SEGK (NNODE / SEG)  // 512

typedef __bf16 bf16x8 __attribute__((ext_vector_type(8)));
typedef float f32x4 __attribute__((ext_vector_type(4)));

__device__ __forceinline__ unsigned short f2b(float f) {
  unsigned int u = __float_as_uint(f);
  u += 0x7fffu + ((u >> 16) & 1u);  // RTNE
  return (unsigned short)(u >> 16);
}

// One kernel: [0,3072) convert x -> bf16; [3072,3168) transpose W1; rest W2.
__global__ __launch_bounds__(256) void prep_kernel(const float* __restrict__ x,
                                                   const float* __restrict__ W1,
                                                   const float* __restrict__ W2,
                                                   unsigned short* __restrict__ xb,
                                                   unsigned short* __restrict__ W1t,
                                                   unsigned short* __restrict__ W2t) {
  __shared__ float tile[64][65];
  int b = blockIdx.x, t = threadIdx.x;
  if (b < 3072) {  // convert x: 4096*768/4 quads
    int i = b * 256 + t;
    float4 v = ((const float4*)x)[i];
    ushort4 o;
    o.x = f2b(v.x); o.y = f2b(v.y); o.z = f2b(v.z); o.w = f2b(v.w);
    ((ushort4*)xb)[i] = o;
    return;
  }
  const float* W; unsigned short* Wt; int K, N, n0, k0;
  if (b < 3072 + 96) {  // W1 [768,512] -> W1t [512,768]
    int b2 = b - 3072; W = W1; Wt = W1t; K = 768; N = 512;
    n0 = (b2 & 7) * 64; k0 = (b2 >> 3) * 64;
  } else {              // W2 [512,128] -> W2t [128,512]
    int b3 = b - 3072 - 96; W = W2; Wt = W2t; K = 512; N = 128;
    n0 = (b3 & 1) * 64; k0 = (b3 >> 1) * 64;
  }
  for (int p = 0; p < 16; p++) {
    int e = p * 256 + t;
    int rr = e >> 6, cc = e & 63;
    tile[rr][cc] = W[(size_t)(k0 + rr) * N + n0 + cc];
  }
  __syncthreads();
  for (int p = 0; p < 16; p++) {
    int e = p * 256 + t;
    int rr = e >> 6, cc = e & 63;  // rr: n-dir, cc: k-dir
    Wt[(size_t)(n0 + rr) * K + k0 + cc] = f2b(tile[cc][rr]);
  }
}

// C[M,N] = A[M,K] x Bt[N,K]^T. bf16 in, fp32 out. BK=32, 256 thr = 4 waves
// (2x2), each wave (BM/32)x(BN/32) frags of 16x16x32 MFMA.
template <int BM, int BN>
__global__ __launch_bounds__(256) void mfma_gemm_bt(const unsigned short* __restrict__ A,
                                                    const unsigned short* __restrict__ Bt,
                                                    float* __restrict__ C,
                                                    int M, int N, int K) {
  __shared__ __align__(16) unsigned short As[BM * 40];
  __shared__ __align__(16) unsigned short Bs[BN * 40];
  constexpr int WM = BM / 2, WN = BN / 2;
  constexpr int FI = WM / 16, FJ = WN / 16;
  constexpr int NA = BM * 32 / (256 * 8);  // uint4 loads per thread for A
  constexpr int NB = BN * 32 / (256 * 8);
  int tid = threadIdx.x;
  int lane = tid & 63, wave = tid >> 6;
  int wm = (wave >> 1) * WM, wn = (wave & 1) * WN;
  int m0 = blockIdx.y * BM, n0 = blockIdx.x * BN;
  int fm = lane & 15, fq = lane >> 4;
  f32x4 acc[FI][FJ] = {};
  for (int k0 = 0; k0 < K; k0 += 32) {
    uint4 ar[NA], br[NB];
#pragma unroll
    for (int q = 0; q < NA; q++) {
      int e = (q * 256 + tid) * 8;
      int r = e >> 5, kk = e & 31;
      ar[q] = *(const uint4*)(A + (size_t)(m0 + r) * K + k0 + kk);
    }
#pragma unroll
    for (int q = 0; q < NB; q++) {
      int e = (q * 256 + tid) * 8;
      int r = e >> 5, kk = e & 31;
      br[q] = *(const uint4*)(Bt + (size_t)(n0 + r) * K + k0 + kk);
    }
    __syncthreads();
#pragma unroll
    for (int q = 0; q < NA; q++) {
      int e = (q * 256 + tid) * 8;
      int r = e >> 5, kk = e & 31;
      *(uint4*)&As[r * 40 + kk] = ar[q];
    }
#pragma unroll
    for (int q = 0; q < NB; q++) {
      int e = (q * 256 + tid) * 8;
      int r = e >> 5, kk = e & 31;
      *(uint4*)&Bs[r * 40 + kk] = br[q];
    }
    __syncthreads();
    bf16x8 af[FI], bfr[FJ];
#pragma unroll
    for (int i = 0; i < FI; i++)
      af[i] = *(const bf16x8*)&As[(wm + i * 16 + fm) * 40 + fq * 8];
#pragma unroll
    for (int j = 0; j < FJ; j++)
      bfr[j] = *(const bf16x8*)&Bs[(wn + j * 16 + fm) * 40 + fq * 8];
#pragma unroll
    for (int i = 0; i < FI; i++)
#pragma unroll
      for (int j = 0; j < FJ; j++)
        acc[i][j] = __builtin_amdgcn_mfma_f32_16x16x32_bf16(af[i], bfr[j], acc[i][j], 0, 0, 0);
  }
#pragma unroll
  for (int i = 0; i < FI; i++) {
#pragma unroll
    for (int j = 0; j < FJ; j++) {
      int r = m0 + wm + i * 16 + fq * 4;
      int ccol = n0 + wn + j * 16 + fm;
#pragma unroll
      for (int reg = 0; reg < 4; reg++)
        C[(size_t)(r + reg) * N + ccol] = acc[i][j][reg];
    }
  }
}

// s[h][n], t[h][n] via one wave per (node, head); shuffle reduce, no LDS.
__global__ void st_kernel(const float* __restrict__ h,
                          const float* __restrict__ asrc,
                          const float* __restrict__ adst,
                          float* __restrict__ s, float* __restrict__ t, int H) {
  int n = blockIdx.x;
  int wave = threadIdx.x >> 6, lane = threadIdx.x & 63;
  int HC = H * CDIM;
  float2 hv = *(const float2*)&h[(size_t)n * HC + wave * CDIM + lane * 2];
  float2 av = *(const float2*)&asrc[wave * CDIM + lane * 2];
  float2 dv = *(const float2*)&adst[wave * CDIM + lane * 2];
  float ps = hv.x * av.x + hv.y * av.y;
  float pt = hv.x * dv.x + hv.y * dv.y;
#pragma unroll
  for (int o = 32; o > 0; o >>= 1) {
    ps += __shfl_down(ps, o, 64);
    pt += __shfl_down(pt, o, 64);
  }
  if (lane == 0) {
    s[(size_t)wave * NNODE + n] = ps;
    t[(size_t)wave * NNODE + n] = pt;
  }
}

// Segmented rank sort, pass 1: partial rank counts over a 512-key segment.
// grid (NNODE/256, SEG, H). rank_i = #{j: kj<ki || (kj==ki && j<i)} — exact perm.
__global__ __launch_bounds__(256) void rank_count_kernel(const float* __restrict__ s,
                                                         int* __restrict__ partial) {
  __shared__ __align__(16) float keys[SEGK];
  int hh = blockIdx.z, seg = blockIdx.y, tid = threadIdx.x;
  const float* sp = s + (size_t)hh * NNODE;
  for (int k = tid; k < SEGK; k += 256) keys[k] = sp[seg * SEGK + k];
  __syncthreads();
  int mi = blockIdx.x * 256 + tid;
  float mk = sp[mi];
  int jbase = seg * SEGK;
  int cnt = 0;
#pragma unroll 4
  for (int j = 0; j < SEGK; j += 4) {
    float4 kv = *(const float4*)&keys[j];
    int jj = jbase + j;
    cnt += (kv.x < mk) || (kv.x == mk && (jj + 0) < mi);
    cnt += (kv.y < mk) || (kv.y == mk && (jj + 1) < mi);
    cnt += (kv.z < mk) || (kv.z == mk && (jj + 2) < mi);
    cnt += (kv.w < mk) || (kv.w == mk && (jj + 3) < mi);
  }
  partial[((size_t)hh * SEG + seg) * NNODE + mi] = cnt;
}

// Pass 2: combine partials, scatter keys+indices to sorted position.
__global__ __launch_bounds__(256) void rank_scatter_kernel(const float* __restrict__ s,
                                                           const int* __restrict__ partial,
                                                           float* __restrict__ ss,
                                                           int* __restrict__ si) {
  int hh = blockIdx.y;
  int mi = blockIdx.x * 256 + threadIdx.x;
  int rank = 0;
#pragma unroll
  for (int g = 0; g < SEG; g++) rank += partial[((size_t)hh * SEG + g) * NNODE + mi];
  float mk = s[(size_t)hh * NNODE + mi];
  ss[(size_t)hh * NNODE + rank] = mk;
  si[(size_t)hh * NNODE + rank] = mi;
}

// Pass A: per-chunk partial sums of e^{s}*h (P) and e^{0.2s}*h (M); z at col 128.
__global__ __launch_bounds__(128) void passA_kernel(const float* __restrict__ h,
                                                    const float* __restrict__ ss,
                                                    const int* __restrict__ si,
                                                    float* __restrict__ partP,
                                                    float* __restrict__ partM, int H) {
  int b = blockIdx.x, hh = b / NCHUNK, ci = b % NCHUNK;
  int c = threadIdx.x;
  int HC = H * CDIM;
  int base = ci * CHUNK;
  float sp = 0.f, sm = 0.f, zp = 0.f, zm = 0.f;
  for (int kk = 0; kk < CHUNK; kk++) {
    int k = base + kk;
    float sv = ss[(size_t)hh * NNODE + k];
    int id = si[(size_t)hh * NNODE + k];
    float v = h[(size_t)id * HC + hh * CDIM + c];
    float ep = expf(sv), em = expf(NEG * sv);
    sp = fmaf(ep, v, sp);
    sm = fmaf(em, v, sm);
    zp += ep; zm += em;  // redundant across threads (cheap)
  }
  size_t o = ((size_t)hh * NCHUNK + ci) * TW;
  partP[o + c] = sp;
  partM[o + c] = sm;
  if (c == 0) { partP[o + 128] = zp; partM[o + 128] = zm; }
}

// Pass C (with fused carry combine): full tables, z at col 128.
// PP[k] = sum_{r<k} e^{0.2 s}h ; SS[k] = sum_{r>=k} e^{s}h (and z analogs).
__global__ __launch_bounds__(128) void passC_kernel(const float* __restrict__ h,
                                                    const float* __restrict__ ss,
                                                    const int* __restrict__ si,
                                                    const float* __restrict__ partP,
                                                    const float* __restrict__ partM,
                                                    float* __restrict__ SS,
                                                    float* __restrict__ PP, int H) {
  int b = blockIdx.x, hh = b / NCHUNK, ci = b % NCHUNK;
  int c = threadIdx.x;
  int HC = H * CDIM;
  int base = ci * CHUNK;
  size_t hb = (size_t)hh * (NNODE + 1);
  // in-block carry combine (replaces passB)
  float cm = 0.f, cp = 0.f, zcm = 0.f, zcp = 0.f;
  for (int g = 0; g < NCHUNK; g++) {
    size_t o = ((size_t)hh * NCHUNK + g) * TW;
    if (g < ci)      { cm += partM[o + c]; zcm += partM[o + 128]; }
    else if (g > ci) { cp += partP[o + c]; zcp += partP[o + 128]; }
  }
  float runm = cm, runzm = zcm;
  for (int kk = 0; kk < CHUNK; kk++) {
    int k = base + kk;
    PP[(hb + k) * TW + c] = runm;
    if (c == 0) PP[(hb + k) * TW + 128] = runzm;
    float sv = ss[(size_t)hh * NNODE + k];
    int id = si[(size_t)hh * NNODE + k];
    float v = h[(size_t)id * HC + hh * CDIM + c];
    float em = expf(NEG * sv);
    runm = fmaf(em, v, runm);
    runzm += em;
  }
  if (ci == NCHUNK - 1) {
    PP[(hb + NNODE) * TW + c] = runm;
    if (c == 0) PP[(hb + NNODE) * TW + 128] = runzm;
  }
  float runp = cp, runzp = zcp;
  for (int kk = CHUNK - 1; kk >= 0; kk--) {
    int k = base + kk;
    float sv = ss[(size_t)hh * NNODE + k];
    int id = si[(size_t)hh * NNODE + k];
    float v = h[(size_t)id * HC + hh * CDIM + c];
    float ep = expf(sv);
    runp = fmaf(ep, v, runp);
    runzp += ep;
    SS[(hb + k) * TW + c] = runp;
    if (c == 0) SS[(hb + k) * TW + 128] = runzp;
  }
  if (ci == NCHUNK - 1) {
    SS[(hb + NNODE) * TW + c] = 0.f;
    if (c == 0) SS[(hb + NNODE) * TW + 128] = 0.f;
  }
}

// Per (dest, head): binary search split point, combine tables, +bias, ELU.
// OUT = unsigned short (bf16, feeds MFMA GEMM2) or float.
template <typename OUT>
__global__ __launch_bounds__(128) void attend_kernel(const float* __restrict__ SS,
                                                     const float* __restrict__ PP,
                                                     const float* __restrict__ ss,
                                                     const float* __restrict__ tt,
                                                     const float* __restrict__ bias,
                                                     OUT* __restrict__ out, int H) {
  int b = blockIdx.x;
  int n = b / H, hh = b % H;
  int c = threadIdx.x;
  float tv = tt[(size_t)hh * NNODE + n];
  const float* sp = ss + (size_t)hh * NNODE;
  float thr = -tv;
  int lo = 0, hi = NNODE;
  while (lo < hi) { int mid = (lo + hi) >> 1; if (sp[mid] < thr) lo = mid + 1; else hi = mid; }
  size_t hb = (size_t)hh * (NNODE + 1);
  float wp = expf(tv), wm = expf(NEG * tv);
  float num = wp * SS[(hb + lo) * TW + c] + wm * PP[(hb + lo) * TW + c];
  float Z = wp * SS[(hb + lo) * TW + 128] + wm * PP[(hb + lo) * TW + 128];
  float o = num / Z + bias[hh * CDIM + c];
  float r = (o > 0.f) ? o : (expf(o) - 1.f);
  if constexpr (sizeof(OUT) == 2)
    out[(size_t)n * (H * CDIM) + hh * CDIM + c] = f2b(r);
  else
    out[(size_t)n * (H * CDIM) + hh * CDIM + c] = r;
}

__global__ __launch_bounds__(256) void mean_kernel(const float* __restrict__ x,
                                                   float* __restrict__ m) {
  __shared__ float red[256];
  int c = blockIdx.x, tid = threadIdx.x;
  float acc = 0.f;
  for (int i = tid; i < NNODE; i += 256) acc += x[(size_t)i * CDIM + c];
  red[tid] = acc; __syncthreads();
  for (int o = 128; o > 0; o >>= 1) { if (tid < o) red[tid] += red[tid + o]; __syncthreads(); }
  if (tid == 0) m[c] = red[0] * (1.f / NNODE);
}

__global__ __launch_bounds__(256) void fc_kernel(const float* __restrict__ m,
                                                 const float* __restrict__ fcW,
                                                 const float* __restrict__ fcb,
                                                 float* __restrict__ out) {
  int d = blockIdx.x * 256 + threadIdx.x;  // 768 total
  float acc = fcb[d];
  for (int c2 = 0; c2 < CDIM; c2++) acc = fmaf(m[c2], fcW[c2 * 768 + d], acc);
  out[d] = acc;
}

extern "C" void kernel_launch(void* const* d_in, const int* in_sizes, int n_in,
                              void* d_out, int out_size, void* d_ws, size_t ws_size,
                              hipStream_t stream) {
  const float* x   = (const float*)d_in[0];
  const float* W1  = (const float*)d_in[1];
  const float* as1 = (const float*)d_in[2];
  const float* ad1 = (const float*)d_in[3];
  const float* b1  = (const float*)d_in[4];
  const float* W2  = (const float*)d_in[5];
  const float* as2 = (const float*)d_in[6];
  const float* ad2 = (const float*)d_in[7];
  const float* b2  = (const float*)d_in[8];
  const float* fcW = (const float*)d_in[9];
  const float* fcb = (const float*)d_in[10];

  float* ws = (float*)d_ws;
  size_t off = 0;
  auto alloc = [&](size_t nfloats) { float* p = ws + off; off += nfloats; return p; };

  float* h1  = alloc((size_t)NNODE * 512);
  float* x2f = alloc((size_t)NNODE * 512);   // first half: x2b bf16; tail: W2t
  float* h2  = alloc((size_t)NNODE * 128);
  float* x3  = alloc((size_t)NNODE * 128);
  float* s1  = alloc((size_t)4 * NNODE);
  float* t1  = alloc((size_t)4 * NNODE);
  float* sS1 = alloc((size_t)4 * NNODE);
  int*   sI1 = (int*)alloc((size_t)4 * NNODE);
  float* SS1 = alloc((size_t)4 * (NNODE + 1) * TW);
  float* PP1 = alloc((size_t)4 * (NNODE + 1) * TW);
  float* pP1 = alloc((size_t)4 * NCHUNK * TW);
  float* pM1 = alloc((size_t)4 * NCHUNK * TW);
  float* s2  = alloc(NNODE);
  float* t2  = alloc(NNODE);
  float* sS2 = alloc(NNODE);
  int*   sI2 = (int*)alloc(NNODE);
  float* SS2 = alloc((size_t)(NNODE + 1) * TW);
  float* PP2 = alloc((size_t)(NNODE + 1) * TW);
  float* pP2 = alloc((size_t)NCHUNK * TW);
  float* pM2 = alloc((size_t)NCHUNK * TW);
  float* mv  = alloc(128);
  int*   rparts = (int*)alloc((size_t)4 * SEG * NNODE);

  // bf16 staging aliased into PP1/SS1 (first written by passC1, strictly after
  // mfma_gemm_bt<128,64> last reads them — stream ordered).
  unsigned short* xb  = (unsigned short*)PP1;  // 4096x768 bf16 = 6.3 MB (< 8.65 MB)
  unsigned short* W1t = (unsigned short*)SS1;  // 512x768 bf16
  unsigned short* x2b = (unsigned short*)x2f;                       // 4096x512 bf16
  unsigned short* W2t = (unsigned short*)(x2f + NNODE * 256 + 64);  // 128x512 bf16

  // Prep: convert x + transpose/cast W1, W2 (one kernel)
  prep_kernel<<<3072 + 96 + 16, 256, 0, stream>>>(x, W1, W2, xb, W1t, W2t);
  // Layer 1
  mfma_gemm_bt<128, 64><<<dim3(512 / 64, NNODE / 128), 256, 0, stream>>>(xb, W1t, h1, NNODE, 512, 768);
  st_kernel<<<NNODE, 4 * 64, 0, stream>>>(h1, as1, ad1, s1, t1, 4);
  rank_count_kernel<<<dim3(NNODE / 256, SEG, 4), 256, 0, stream>>>(s1, rparts);
  rank_scatter_kernel<<<dim3(NNODE / 256, 4), 256, 0, stream>>>(s1, rparts, sS1, sI1);
  passA_kernel<<<4 * NCHUNK, 128, 0, stream>>>(h1, sS1, sI1, pP1, pM1, 4);
  passC_kernel<<<4 * NCHUNK, 128, 0, stream>>>(h1, sS1, sI1, pP1, pM1, SS1, PP1, 4);
  attend_kernel<unsigned short><<<NNODE * 4, 128, 0, stream>>>(SS1, PP1, sS1, t1, b1, x2b, 4);
  // Layer 2
  mfma_gemm_bt<64, 64><<<dim3(128 / 64, NNODE / 64), 256, 0, stream>>>(x2b, W2t, h2, NNODE, 128, 512);
  st_kernel<<<NNODE, 1 * 64, 0, stream>>>(h2, as2, ad2, s2, t2, 1);
  rank_count_kernel<<<dim3(NNODE / 256, SEG, 1), 256, 0, stream>>>(s2, rparts);
  rank_scatter_kernel<<<dim3(NNODE / 256, 1), 256, 0, stream>>>(s2, rparts, sS2, sI2);
  passA_kernel<<<NCHUNK, 128, 0, stream>>>(h2, sS2, sI2, pP2, pM2, 1);
  passC_kernel<<<NCHUNK, 128, 0, stream>>>(h2, sS2, sI2, pP2, pM2, SS2, PP2, 1);
  attend_kernel<float><<<NNODE, 128, 0, stream>>>(SS2, PP2, sS2, t2, b2, x3, 1);
  // Readout
  mean_kernel<<<128, 256, 0, stream>>>(x3, mv);
  fc_kernel<<<3, 256, 0, stream>>>(mv, fcW, fcb, (float*)d_out);
}

// Round 6
// 254.602 us; speedup vs baseline: 1.1509x; 1.1509x over previous
//
#include <hip/hip_runtime.h>
#include <hip/hip_bf16.h>

// FacePartGAT: dense-graph GATConv x2 + mean + fc on MI355X. ALL I/O fp32.
// Key trick: e[i,j] = leaky_relu(t_i + s_j) => softmax aggregation factorizes
// after sorting sources by s_j:
//   out_i = (e^{t_i} SS[k_i] + e^{0.2 t_i} PP[k_i]) / (e^{t_i} zS[k_i] + e^{0.2 t_i} zP[k_i])
// SS/PP suffix/prefix sums over sorted rank, k_i = lower_bound(sortedS, -t_i).
// Exact (reordered summation) — avoids the O(N^2 C) dense aggregation.
// Round 6: latency-bound table build fixed. passB back as register-scan
// (all 64 partials in flight); passA/passC gather in unroll-8 batches;
// passC scans from LDS scratch instead of chained global gathers.
// GEMM1 back to 128x128 (round-4-proven).

#define NNODE 4096
#define CDIM 128
#define TW 132           // table width: 128 features + z at col 128, pad to 132
#define NEG 0.2f
#define CHUNK 64
#define NCHUNK 64        // NNODE / CHUNK
#define SEG 8
#define SEGK (NNODE / SEG)  // 512

typedef __bf16 bf16x8 __attribute__((ext_vector_type(8)));
typedef float f32x4 __attribute__((ext_vector_type(4)));

__device__ __forceinline__ unsigned short f2b(float f) {
  unsigned int u = __float_as_uint(f);
  u += 0x7fffu + ((u >> 16) & 1u);  // RTNE
  return (unsigned short)(u >> 16);
}

// One kernel: [0,3072) convert x -> bf16; [3072,3168) transpose W1; rest W2.
__global__ __launch_bounds__(256) void prep_kernel(const float* __restrict__ x,
                                                   const float* __restrict__ W1,
                                                   const float* __restrict__ W2,
                                                   unsigned short* __restrict__ xb,
                                                   unsigned short* __restrict__ W1t,
                                                   unsigned short* __restrict__ W2t) {
  __shared__ float tile[64][65];
  int b = blockIdx.x, t = threadIdx.x;
  if (b < 3072) {  // convert x: 4096*768/4 quads
    int i = b * 256 + t;
    float4 v = ((const float4*)x)[i];
    ushort4 o;
    o.x = f2b(v.x); o.y = f2b(v.y); o.z = f2b(v.z); o.w = f2b(v.w);
    ((ushort4*)xb)[i] = o;
    return;
  }
  const float* W; unsigned short* Wt; int K, N, n0, k0;
  if (b < 3072 + 96) {  // W1 [768,512] -> W1t [512,768]
    int b2 = b - 3072; W = W1; Wt = W1t; K = 768; N = 512;
    n0 = (b2 & 7) * 64; k0 = (b2 >> 3) * 64;
  } else {              // W2 [512,128] -> W2t [128,512]
    int b3 = b - 3072 - 96; W = W2; Wt = W2t; K = 512; N = 128;
    n0 = (b3 & 1) * 64; k0 = (b3 >> 1) * 64;
  }
  for (int p = 0; p < 16; p++) {
    int e = p * 256 + t;
    int rr = e >> 6, cc = e & 63;
    tile[rr][cc] = W[(size_t)(k0 + rr) * N + n0 + cc];
  }
  __syncthreads();
  for (int p = 0; p < 16; p++) {
    int e = p * 256 + t;
    int rr = e >> 6, cc = e & 63;  // rr: n-dir, cc: k-dir
    Wt[(size_t)(n0 + rr) * K + k0 + cc] = f2b(tile[cc][rr]);
  }
}

// C[M,N] = A[M,K] x Bt[N,K]^T. bf16 in, fp32 out. BK=32, 256 thr = 4 waves
// (2x2), each wave (BM/32)x(BN/32) frags of 16x16x32 MFMA.
template <int BM, int BN>
__global__ __launch_bounds__(256) void mfma_gemm_bt(const unsigned short* __restrict__ A,
                                                    const unsigned short* __restrict__ Bt,
                                                    float* __restrict__ C,
                                                    int M, int N, int K) {
  __shared__ __align__(16) unsigned short As[BM * 40];
  __shared__ __align__(16) unsigned short Bs[BN * 40];
  constexpr int WM = BM / 2, WN = BN / 2;
  constexpr int FI = WM / 16, FJ = WN / 16;
  constexpr int NA = BM * 32 / (256 * 8);
  constexpr int NB = BN * 32 / (256 * 8);
  int tid = threadIdx.x;
  int lane = tid & 63, wave = tid >> 6;
  int wm = (wave >> 1) * WM, wn = (wave & 1) * WN;
  int m0 = blockIdx.y * BM, n0 = blockIdx.x * BN;
  int fm = lane & 15, fq = lane >> 4;
  f32x4 acc[FI][FJ] = {};
  for (int k0 = 0; k0 < K; k0 += 32) {
    uint4 ar[NA], br[NB];
#pragma unroll
    for (int q = 0; q < NA; q++) {
      int e = (q * 256 + tid) * 8;
      int r = e >> 5, kk = e & 31;
      ar[q] = *(const uint4*)(A + (size_t)(m0 + r) * K + k0 + kk);
    }
#pragma unroll
    for (int q = 0; q < NB; q++) {
      int e = (q * 256 + tid) * 8;
      int r = e >> 5, kk = e & 31;
      br[q] = *(const uint4*)(Bt + (size_t)(n0 + r) * K + k0 + kk);
    }
    __syncthreads();
#pragma unroll
    for (int q = 0; q < NA; q++) {
      int e = (q * 256 + tid) * 8;
      int r = e >> 5, kk = e & 31;
      *(uint4*)&As[r * 40 + kk] = ar[q];
    }
#pragma unroll
    for (int q = 0; q < NB; q++) {
      int e = (q * 256 + tid) * 8;
      int r = e >> 5, kk = e & 31;
      *(uint4*)&Bs[r * 40 + kk] = br[q];
    }
    __syncthreads();
    bf16x8 af[FI], bfr[FJ];
#pragma unroll
    for (int i = 0; i < FI; i++)
      af[i] = *(const bf16x8*)&As[(wm + i * 16 + fm) * 40 + fq * 8];
#pragma unroll
    for (int j = 0; j < FJ; j++)
      bfr[j] = *(const bf16x8*)&Bs[(wn + j * 16 + fm) * 40 + fq * 8];
#pragma unroll
    for (int i = 0; i < FI; i++)
#pragma unroll
      for (int j = 0; j < FJ; j++)
        acc[i][j] = __builtin_amdgcn_mfma_f32_16x16x32_bf16(af[i], bfr[j], acc[i][j], 0, 0, 0);
  }
#pragma unroll
  for (int i = 0; i < FI; i++) {
#pragma unroll
    for (int j = 0; j < FJ; j++) {
      int r = m0 + wm + i * 16 + fq * 4;
      int ccol = n0 + wn + j * 16 + fm;
#pragma unroll
      for (int reg = 0; reg < 4; reg++)
        C[(size_t)(r + reg) * N + ccol] = acc[i][j][reg];
    }
  }
}

// s[h][n], t[h][n] via one wave per (node, head); shuffle reduce, no LDS.
__global__ void st_kernel(const float* __restrict__ h,
                          const float* __restrict__ asrc,
                          const float* __restrict__ adst,
                          float* __restrict__ s, float* __restrict__ t, int H) {
  int n = blockIdx.x;
  int wave = threadIdx.x >> 6, lane = threadIdx.x & 63;
  int HC = H * CDIM;
  float2 hv = *(const float2*)&h[(size_t)n * HC + wave * CDIM + lane * 2];
  float2 av = *(const float2*)&asrc[wave * CDIM + lane * 2];
  float2 dv = *(const float2*)&adst[wave * CDIM + lane * 2];
  float ps = hv.x * av.x + hv.y * av.y;
  float pt = hv.x * dv.x + hv.y * dv.y;
#pragma unroll
  for (int o = 32; o > 0; o >>= 1) {
    ps += __shfl_down(ps, o, 64);
    pt += __shfl_down(pt, o, 64);
  }
  if (lane == 0) {
    s[(size_t)wave * NNODE + n] = ps;
    t[(size_t)wave * NNODE + n] = pt;
  }
}

// Segmented rank sort, pass 1: partial rank counts over a 512-key segment.
__global__ __launch_bounds__(256) void rank_count_kernel(const float* __restrict__ s,
                                                         int* __restrict__ partial) {
  __shared__ __align__(16) float keys[SEGK];
  int hh = blockIdx.z, seg = blockIdx.y, tid = threadIdx.x;
  const float* sp = s + (size_t)hh * NNODE;
  for (int k = tid; k < SEGK; k += 256) keys[k] = sp[seg * SEGK + k];
  __syncthreads();
  int mi = blockIdx.x * 256 + tid;
  float mk = sp[mi];
  int jbase = seg * SEGK;
  int cnt = 0;
#pragma unroll 4
  for (int j = 0; j < SEGK; j += 4) {
    float4 kv = *(const float4*)&keys[j];
    int jj = jbase + j;
    cnt += (kv.x < mk) || (kv.x == mk && (jj + 0) < mi);
    cnt += (kv.y < mk) || (kv.y == mk && (jj + 1) < mi);
    cnt += (kv.z < mk) || (kv.z == mk && (jj + 2) < mi);
    cnt += (kv.w < mk) || (kv.w == mk && (jj + 3) < mi);
  }
  partial[((size_t)hh * SEG + seg) * NNODE + mi] = cnt;
}

// Pass 2: combine partials, scatter keys+indices to sorted position.
__global__ __launch_bounds__(256) void rank_scatter_kernel(const float* __restrict__ s,
                                                           const int* __restrict__ partial,
                                                           float* __restrict__ ss,
                                                           int* __restrict__ si) {
  int hh = blockIdx.y;
  int mi = blockIdx.x * 256 + threadIdx.x;
  int rank = 0;
#pragma unroll
  for (int g = 0; g < SEG; g++) rank += partial[((size_t)hh * SEG + g) * NNODE + mi];
  float mk = s[(size_t)hh * NNODE + mi];
  ss[(size_t)hh * NNODE + rank] = mk;
  si[(size_t)hh * NNODE + rank] = mi;
}

// Pass A: per-chunk partial sums of e^{s}*h (P) and e^{0.2s}*h (M); z at col 128.
// ids/exps staged in LDS; h gathered in unroll-8 register batches (pipelined).
__global__ __launch_bounds__(128) void passA_kernel(const float* __restrict__ h,
                                                    const float* __restrict__ ss,
                                                    const int* __restrict__ si,
                                                    float* __restrict__ partP,
                                                    float* __restrict__ partM, int H) {
  __shared__ float eP[CHUNK], eM[CHUNK];
  __shared__ int ids[CHUNK];
  int b = blockIdx.x, hh = b / NCHUNK, ci = b % NCHUNK;
  int c = threadIdx.x;
  int HC = H * CDIM;
  int base = ci * CHUNK;
  if (c < CHUNK) {
    float sv = ss[(size_t)hh * NNODE + base + c];
    ids[c] = si[(size_t)hh * NNODE + base + c];
    eP[c] = expf(sv);
    eM[c] = expf(NEG * sv);
  }
  __syncthreads();
  float sp = 0.f, sm = 0.f;
  for (int kb = 0; kb < CHUNK; kb += 8) {
    float v[8];
#pragma unroll
    for (int j = 0; j < 8; j++)
      v[j] = h[(size_t)ids[kb + j] * HC + hh * CDIM + c];
#pragma unroll
    for (int j = 0; j < 8; j++) {
      sp = fmaf(eP[kb + j], v[j], sp);
      sm = fmaf(eM[kb + j], v[j], sm);
    }
  }
  size_t o = ((size_t)hh * NCHUNK + ci) * TW;
  partP[o + c] = sp;
  partM[o + c] = sm;
  if (c == 0) {
    float zp = 0.f, zm = 0.f;
#pragma unroll
    for (int k = 0; k < CHUNK; k++) { zp += eP[k]; zm += eM[k]; }
    partP[o + 128] = zp;
    partM[o + 128] = zm;
  }
}

// Pass B: chunk carries. One block per head, thread c handles column c
// (c==128 -> z). All 64 partials loaded into registers (in flight), then
// register prefix (M) / suffix (P) scans.
__global__ __launch_bounds__(192) void passB_kernel(const float* __restrict__ partP,
                                                    const float* __restrict__ partM,
                                                    float* __restrict__ carryP,
                                                    float* __restrict__ carryM) {
  int hh = blockIdx.x, c = threadIdx.x;
  if (c > 128) return;
  float vM[NCHUNK], vP[NCHUNK];
#pragma unroll
  for (int g = 0; g < NCHUNK; g++) {
    size_t o = ((size_t)hh * NCHUNK + g) * TW + c;
    vM[g] = partM[o];
    vP[g] = partP[o];
  }
  float run = 0.f;
#pragma unroll
  for (int g = 0; g < NCHUNK; g++) {
    carryM[((size_t)hh * NCHUNK + g) * TW + c] = run;
    run += vM[g];
  }
  run = 0.f;
#pragma unroll
  for (int g = NCHUNK - 1; g >= 0; g--) {
    carryP[((size_t)hh * NCHUNK + g) * TW + c] = run;
    run += vP[g];
  }
}

// Pass C: full tables, z at col 128. Gather h once into LDS scratch
// (per-thread column, batched global loads), then scan twice from LDS.
__global__ __launch_bounds__(128) void passC_kernel(const float* __restrict__ h,
                                                    const float* __restrict__ ss,
                                                    const int* __restrict__ si,
                                                    const float* __restrict__ carryP,
                                                    const float* __restrict__ carryM,
                                                    float* __restrict__ SS,
                                                    float* __restrict__ PP, int H) {
  __shared__ float hrow[CHUNK][CDIM];  // 32 KB; hrow[k][c] touched only by thread c
  __shared__ float eP[CHUNK], eM[CHUNK];
  __shared__ int ids[CHUNK];
  int b = blockIdx.x, hh = b / NCHUNK, ci = b % NCHUNK;
  int c = threadIdx.x;
  int HC = H * CDIM;
  int base = ci * CHUNK;
  size_t hb = (size_t)hh * (NNODE + 1);
  if (c < CHUNK) {
    float sv = ss[(size_t)hh * NNODE + base + c];
    ids[c] = si[(size_t)hh * NNODE + base + c];
    eP[c] = expf(sv);
    eM[c] = expf(NEG * sv);
  }
  __syncthreads();
  for (int kb = 0; kb < CHUNK; kb += 8) {
    float v[8];
#pragma unroll
    for (int j = 0; j < 8; j++)
      v[j] = h[(size_t)ids[kb + j] * HC + hh * CDIM + c];
#pragma unroll
    for (int j = 0; j < 8; j++) hrow[kb + j][c] = v[j];
  }
  // no sync needed: hrow[k][c] written and read by the same thread
  size_t co = ((size_t)hh * NCHUNK + ci) * TW;
  float runm = carryM[co + c], runzm = carryM[co + 128];
#pragma unroll 8
  for (int k = 0; k < CHUNK; k++) {
    size_t row = (hb + base + k) * TW;
    PP[row + c] = runm;
    if (c == 0) PP[row + 128] = runzm;
    runm = fmaf(eM[k], hrow[k][c], runm);
    runzm += eM[k];
  }
  if (ci == NCHUNK - 1) {
    size_t row = (hb + NNODE) * TW;
    PP[row + c] = runm;
    if (c == 0) PP[row + 128] = runzm;
  }
  float runp = carryP[co + c], runzp = carryP[co + 128];
#pragma unroll 8
  for (int k = CHUNK - 1; k >= 0; k--) {
    runp = fmaf(eP[k], hrow[k][c], runp);
    runzp += eP[k];
    size_t row = (hb + base + k) * TW;
    SS[row + c] = runp;
    if (c == 0) SS[row + 128] = runzp;
  }
  if (ci == NCHUNK - 1) {
    size_t row = (hb + NNODE) * TW;
    SS[row + c] = 0.f;
    if (c == 0) SS[row + 128] = 0.f;
  }
}

// Per (dest, head): binary search split point, combine tables, +bias, ELU.
// OUT = unsigned short (bf16, feeds MFMA GEMM2) or float.
template <typename OUT>
__global__ __launch_bounds__(128) void attend_kernel(const float* __restrict__ SS,
                                                     const float* __restrict__ PP,
                                                     const float* __restrict__ ss,
                                                     const float* __restrict__ tt,
                                                     const float* __restrict__ bias,
                                                     OUT* __restrict__ out, int H) {
  int b = blockIdx.x;
  int n = b / H, hh = b % H;
  int c = threadIdx.x;
  float tv = tt[(size_t)hh * NNODE + n];
  const float* sp = ss + (size_t)hh * NNODE;
  float thr = -tv;
  int lo = 0, hi = NNODE;
  while (lo < hi) { int mid = (lo + hi) >> 1; if (sp[mid] < thr) lo = mid + 1; else hi = mid; }
  size_t hb = (size_t)hh * (NNODE + 1);
  float wp = expf(tv), wm = expf(NEG * tv);
  float num = wp * SS[(hb + lo) * TW + c] + wm * PP[(hb + lo) * TW + c];
  float Z = wp * SS[(hb + lo) * TW + 128] + wm * PP[(hb + lo) * TW + 128];
  float o = num / Z + bias[hh * CDIM + c];
  float r = (o > 0.f) ? o : (expf(o) - 1.f);
  if constexpr (sizeof(OUT) == 2)
    out[(size_t)n * (H * CDIM) + hh * CDIM + c] = f2b(r);
  else
    out[(size_t)n * (H * CDIM) + hh * CDIM + c] = r;
}

__global__ __launch_bounds__(256) void mean_kernel(const float* __restrict__ x,
                                                   float* __restrict__ m) {
  __shared__ float red[256];
  int c = blockIdx.x, tid = threadIdx.x;
  float acc = 0.f;
  for (int i = tid; i < NNODE; i += 256) acc += x[(size_t)i * CDIM + c];
  red[tid] = acc; __syncthreads();
  for (int o = 128; o > 0; o >>= 1) { if (tid < o) red[tid] += red[tid + o]; __syncthreads(); }
  if (tid == 0) m[c] = red[0] * (1.f / NNODE);
}

__global__ __launch_bounds__(256) void fc_kernel(const float* __restrict__ m,
                                                 const float* __restrict__ fcW,
                                                 const float* __restrict__ fcb,
                                                 float* __restrict__ out) {
  int d = blockIdx.x * 256 + threadIdx.x;  // 768 total
  float acc = fcb[d];
  for (int c2 = 0; c2 < CDIM; c2++) acc = fmaf(m[c2], fcW[c2 * 768 + d], acc);
  out[d] = acc;
}

extern "C" void kernel_launch(void* const* d_in, const int* in_sizes, int n_in,
                              void* d_out, int out_size, void* d_ws, size_t ws_size,
                              hipStream_t stream) {
  const float* x   = (const float*)d_in[0];
  const float* W1  = (const float*)d_in[1];
  const float* as1 = (const float*)d_in[2];
  const float* ad1 = (const float*)d_in[3];
  const float* b1  = (const float*)d_in[4];
  const float* W2  = (const float*)d_in[5];
  const float* as2 = (const float*)d_in[6];
  const float* ad2 = (const float*)d_in[7];
  const float* b2  = (const float*)d_in[8];
  const float* fcW = (const float*)d_in[9];
  const float* fcb = (const float*)d_in[10];

  float* ws = (float*)d_ws;
  size_t off = 0;
  auto alloc = [&](size_t nfloats) { float* p = ws + off; off += nfloats; return p; };

  float* h1  = alloc((size_t)NNODE * 512);
  float* x2f = alloc((size_t)NNODE * 512);   // first half: x2b bf16; tail: W2t
  float* h2  = alloc((size_t)NNODE * 128);
  float* x3  = alloc((size_t)NNODE * 128);
  float* s1  = alloc((size_t)4 * NNODE);
  float* t1  = alloc((size_t)4 * NNODE);
  float* sS1 = alloc((size_t)4 * NNODE);
  int*   sI1 = (int*)alloc((size_t)4 * NNODE);
  float* SS1 = alloc((size_t)4 * (NNODE + 1) * TW);
  float* PP1 = alloc((size_t)4 * (NNODE + 1) * TW);
  float* pP1 = alloc((size_t)4 * NCHUNK * TW);
  float* pM1 = alloc((size_t)4 * NCHUNK * TW);
  float* cP1 = alloc((size_t)4 * NCHUNK * TW);
  float* cM1 = alloc((size_t)4 * NCHUNK * TW);
  float* s2  = alloc(NNODE);
  float* t2  = alloc(NNODE);
  float* sS2 = alloc(NNODE);
  int*   sI2 = (int*)alloc(NNODE);
  float* SS2 = alloc((size_t)(NNODE + 1) * TW);
  float* PP2 = alloc((size_t)(NNODE + 1) * TW);
  float* pP2 = alloc((size_t)NCHUNK * TW);
  float* pM2 = alloc((size_t)NCHUNK * TW);
  float* cP2 = alloc((size_t)NCHUNK * TW);
  float* cM2 = alloc((size_t)NCHUNK * TW);
  float* mv  = alloc(128);
  int*   rparts = (int*)alloc((size_t)4 * SEG * NNODE);

  // bf16 staging aliased into PP1/SS1 (first written by passC1, strictly after
  // gemm1 last reads them — stream ordered).
  unsigned short* xb  = (unsigned short*)PP1;  // 4096x768 bf16 = 6.3 MB (< 8.65 MB)
  unsigned short* W1t = (unsigned short*)SS1;  // 512x768 bf16
  unsigned short* x2b = (unsigned short*)x2f;                       // 4096x512 bf16
  unsigned short* W2t = (unsigned short*)(x2f + NNODE * 256 + 64);  // 128x512 bf16

  // Prep: convert x + transpose/cast W1, W2 (one kernel)
  prep_kernel<<<3072 + 96 + 16, 256, 0, stream>>>(x, W1, W2, xb, W1t, W2t);
  // Layer 1
  mfma_gemm_bt<128, 128><<<dim3(512 / 128, NNODE / 128), 256, 0, stream>>>(xb, W1t, h1, NNODE, 512, 768);
  st_kernel<<<NNODE, 4 * 64, 0, stream>>>(h1, as1, ad1, s1, t1, 4);
  rank_count_kernel<<<dim3(NNODE / 256, SEG, 4), 256, 0, stream>>>(s1, rparts);
  rank_scatter_kernel<<<dim3(NNODE / 256, 4), 256, 0, stream>>>(s1, rparts, sS1, sI1);
  passA_kernel<<<4 * NCHUNK, 128, 0, stream>>>(h1, sS1, sI1, pP1, pM1, 4);
  passB_kernel<<<4, 192, 0, stream>>>(pP1, pM1, cP1, cM1);
  passC_kernel<<<4 * NCHUNK, 128, 0, stream>>>(h1, sS1, sI1, cP1, cM1, SS1, PP1, 4);
  attend_kernel<unsigned short><<<NNODE * 4, 128, 0, stream>>>(SS1, PP1, sS1, t1, b1, x2b, 4);
  // Layer 2
  mfma_gemm_bt<64, 64><<<dim3(128 / 64, NNODE / 64), 256, 0, stream>>>(x2b, W2t, h2, NNODE, 128, 512);
  st_kernel<<<NNODE, 1 * 64, 0, stream>>>(h2, as2, ad2, s2, t2, 1);
  rank_count_kernel<<<dim3(NNODE / 256, SEG, 1), 256, 0, stream>>>(s2, rparts);
  rank_scatter_kernel<<<dim3(NNODE / 256, 1), 256, 0, stream>>>(s2, rparts, sS2, sI2);
  passA_kernel<<<NCHUNK, 128, 0, stream>>>(h2, sS2, sI2, pP2, pM2, 1);
  passB_kernel<<<1, 192, 0, stream>>>(pP2, pM2, cP2, cM2);
  passC_kernel<<<NCHUNK, 128, 0, stream>>>(h2, sS2, sI2, cP2, cM2, SS2, PP2, 1);
  attend_kernel<float><<<NNODE, 128, 0, stream>>>(SS2, PP2, sS2, t2, b2, x3, 1);
  // Readout
  mean_kernel<<<128, 256, 0, stream>>>(x3, mv);
  fc_kernel<<<3, 256, 0, stream>>>(mv, fcW, fcb, (float*)d_out);
}

// Round 7
// 226.438 us; speedup vs baseline: 1.2941x; 1.1244x over previous
//
#include <hip/hip_runtime.h>
#include <hip/hip_bf16.h>

// FacePartGAT: dense-graph GATConv x2 + mean + fc on MI355X. ALL I/O fp32.
// Key trick: e[i,j] = leaky_relu(t_i + s_j) => softmax aggregation factorizes
// after sorting sources by s_j:
//   out_i = (e^{t_i} SS[k_i] + e^{0.2 t_i} PP[k_i]) / (e^{t_i} zS[k_i] + e^{0.2 t_i} zP[k_i])
// SS/PP suffix/prefix sums over sorted rank, k_i = lower_bound(sortedS, -t_i).
// Exact (reordered summation) — avoids the O(N^2 C) dense aggregation.
// Round 7: GEMM occupancy fix. 128x128 tile left only 128 blocks on 256 CUs
// (Occupancy 4.8%, MfmaUtil 2.3%) — latency fully exposed. GEMM1 -> 64x64
// (512 blocks, 2 blocks/CU), GEMM2 -> 32x64 (256 blocks).

#define NNODE 4096
#define CDIM 128
#define TW 132           // table width: 128 features + z at col 128, pad to 132
#define NEG 0.2f
#define CHUNK 64
#define NCHUNK 64        // NNODE / CHUNK
#define SEG 8
#define SEGK (NNODE / SEG)  // 512

typedef __bf16 bf16x8 __attribute__((ext_vector_type(8)));
typedef float f32x4 __attribute__((ext_vector_type(4)));

__device__ __forceinline__ unsigned short f2b(float f) {
  unsigned int u = __float_as_uint(f);
  u += 0x7fffu + ((u >> 16) & 1u);  // RTNE
  return (unsigned short)(u >> 16);
}

// One kernel: [0,3072) convert x -> bf16; [3072,3168) transpose W1; rest W2.
__global__ __launch_bounds__(256) void prep_kernel(const float* __restrict__ x,
                                                   const float* __restrict__ W1,
                                                   const float* __restrict__ W2,
                                                   unsigned short* __restrict__ xb,
                                                   unsigned short* __restrict__ W1t,
                                                   unsigned short* __restrict__ W2t) {
  __shared__ float tile[64][65];
  int b = blockIdx.x, t = threadIdx.x;
  if (b < 3072) {  // convert x: 4096*768/4 quads
    int i = b * 256 + t;
    float4 v = ((const float4*)x)[i];
    ushort4 o;
    o.x = f2b(v.x); o.y = f2b(v.y); o.z = f2b(v.z); o.w = f2b(v.w);
    ((ushort4*)xb)[i] = o;
    return;
  }
  const float* W; unsigned short* Wt; int K, N, n0, k0;
  if (b < 3072 + 96) {  // W1 [768,512] -> W1t [512,768]
    int b2 = b - 3072; W = W1; Wt = W1t; K = 768; N = 512;
    n0 = (b2 & 7) * 64; k0 = (b2 >> 3) * 64;
  } else {              // W2 [512,128] -> W2t [128,512]
    int b3 = b - 3072 - 96; W = W2; Wt = W2t; K = 512; N = 128;
    n0 = (b3 & 1) * 64; k0 = (b3 >> 1) * 64;
  }
  for (int p = 0; p < 16; p++) {
    int e = p * 256 + t;
    int rr = e >> 6, cc = e & 63;
    tile[rr][cc] = W[(size_t)(k0 + rr) * N + n0 + cc];
  }
  __syncthreads();
  for (int p = 0; p < 16; p++) {
    int e = p * 256 + t;
    int rr = e >> 6, cc = e & 63;  // rr: n-dir, cc: k-dir
    Wt[(size_t)(n0 + rr) * K + k0 + cc] = f2b(tile[cc][rr]);
  }
}

// C[M,N] = A[M,K] x Bt[N,K]^T. bf16 in, fp32 out. BK=32, 256 thr = 4 waves
// in a 2x2 grid; wave tile WM=BM/2 (>=16), WN=BN/2. Staging loads guarded so
// BM=32 (As smaller than one full 256-thread pass) works.
template <int BM, int BN>
__global__ __launch_bounds__(256) void mfma_gemm_bt(const unsigned short* __restrict__ A,
                                                    const unsigned short* __restrict__ Bt,
                                                    float* __restrict__ C,
                                                    int M, int N, int K) {
  __shared__ __align__(16) unsigned short As[BM * 40];
  __shared__ __align__(16) unsigned short Bs[BN * 40];
  constexpr int WM = BM / 2, WN = BN / 2;
  constexpr int FI = WM / 16, FJ = WN / 16;
  constexpr int EA = BM * 32 / 8;  // uint4 elements to stage for A
  constexpr int EB = BN * 32 / 8;
  constexpr int NA = (EA + 255) / 256;
  constexpr int NB = (EB + 255) / 256;
  int tid = threadIdx.x;
  int lane = tid & 63, wave = tid >> 6;
  int wm = (wave >> 1) * WM, wn = (wave & 1) * WN;
  int m0 = blockIdx.y * BM, n0 = blockIdx.x * BN;
  int fm = lane & 15, fq = lane >> 4;
  f32x4 acc[FI][FJ] = {};
  for (int k0 = 0; k0 < K; k0 += 32) {
    uint4 ar[NA], br[NB];
#pragma unroll
    for (int q = 0; q < NA; q++) {
      int e = q * 256 + tid;
      if (e < EA) {
        int r = (e * 8) >> 5, kk = (e * 8) & 31;
        ar[q] = *(const uint4*)(A + (size_t)(m0 + r) * K + k0 + kk);
      }
    }
#pragma unroll
    for (int q = 0; q < NB; q++) {
      int e = q * 256 + tid;
      if (e < EB) {
        int r = (e * 8) >> 5, kk = (e * 8) & 31;
        br[q] = *(const uint4*)(Bt + (size_t)(n0 + r) * K + k0 + kk);
      }
    }
    __syncthreads();
#pragma unroll
    for (int q = 0; q < NA; q++) {
      int e = q * 256 + tid;
      if (e < EA) {
        int r = (e * 8) >> 5, kk = (e * 8) & 31;
        *(uint4*)&As[r * 40 + kk] = ar[q];
      }
    }
#pragma unroll
    for (int q = 0; q < NB; q++) {
      int e = q * 256 + tid;
      if (e < EB) {
        int r = (e * 8) >> 5, kk = (e * 8) & 31;
        *(uint4*)&Bs[r * 40 + kk] = br[q];
      }
    }
    __syncthreads();
    bf16x8 af[FI], bfr[FJ];
#pragma unroll
    for (int i = 0; i < FI; i++)
      af[i] = *(const bf16x8*)&As[(wm + i * 16 + fm) * 40 + fq * 8];
#pragma unroll
    for (int j = 0; j < FJ; j++)
      bfr[j] = *(const bf16x8*)&Bs[(wn + j * 16 + fm) * 40 + fq * 8];
#pragma unroll
    for (int i = 0; i < FI; i++)
#pragma unroll
      for (int j = 0; j < FJ; j++)
        acc[i][j] = __builtin_amdgcn_mfma_f32_16x16x32_bf16(af[i], bfr[j], acc[i][j], 0, 0, 0);
  }
#pragma unroll
  for (int i = 0; i < FI; i++) {
#pragma unroll
    for (int j = 0; j < FJ; j++) {
      int r = m0 + wm + i * 16 + fq * 4;
      int ccol = n0 + wn + j * 16 + fm;
#pragma unroll
      for (int reg = 0; reg < 4; reg++)
        C[(size_t)(r + reg) * N + ccol] = acc[i][j][reg];
    }
  }
}

// s[h][n], t[h][n] via one wave per (node, head); shuffle reduce, no LDS.
__global__ void st_kernel(const float* __restrict__ h,
                          const float* __restrict__ asrc,
                          const float* __restrict__ adst,
                          float* __restrict__ s, float* __restrict__ t, int H) {
  int n = blockIdx.x;
  int wave = threadIdx.x >> 6, lane = threadIdx.x & 63;
  int HC = H * CDIM;
  float2 hv = *(const float2*)&h[(size_t)n * HC + wave * CDIM + lane * 2];
  float2 av = *(const float2*)&asrc[wave * CDIM + lane * 2];
  float2 dv = *(const float2*)&adst[wave * CDIM + lane * 2];
  float ps = hv.x * av.x + hv.y * av.y;
  float pt = hv.x * dv.x + hv.y * dv.y;
#pragma unroll
  for (int o = 32; o > 0; o >>= 1) {
    ps += __shfl_down(ps, o, 64);
    pt += __shfl_down(pt, o, 64);
  }
  if (lane == 0) {
    s[(size_t)wave * NNODE + n] = ps;
    t[(size_t)wave * NNODE + n] = pt;
  }
}

// Segmented rank sort, pass 1: partial rank counts over a 512-key segment.
__global__ __launch_bounds__(256) void rank_count_kernel(const float* __restrict__ s,
                                                         int* __restrict__ partial) {
  __shared__ __align__(16) float keys[SEGK];
  int hh = blockIdx.z, seg = blockIdx.y, tid = threadIdx.x;
  const float* sp = s + (size_t)hh * NNODE;
  for (int k = tid; k < SEGK; k += 256) keys[k] = sp[seg * SEGK + k];
  __syncthreads();
  int mi = blockIdx.x * 256 + tid;
  float mk = sp[mi];
  int jbase = seg * SEGK;
  int cnt = 0;
#pragma unroll 4
  for (int j = 0; j < SEGK; j += 4) {
    float4 kv = *(const float4*)&keys[j];
    int jj = jbase + j;
    cnt += (kv.x < mk) || (kv.x == mk && (jj + 0) < mi);
    cnt += (kv.y < mk) || (kv.y == mk && (jj + 1) < mi);
    cnt += (kv.z < mk) || (kv.z == mk && (jj + 2) < mi);
    cnt += (kv.w < mk) || (kv.w == mk && (jj + 3) < mi);
  }
  partial[((size_t)hh * SEG + seg) * NNODE + mi] = cnt;
}

// Pass 2: combine partials, scatter keys+indices to sorted position.
__global__ __launch_bounds__(256) void rank_scatter_kernel(const float* __restrict__ s,
                                                           const int* __restrict__ partial,
                                                           float* __restrict__ ss,
                                                           int* __restrict__ si) {
  int hh = blockIdx.y;
  int mi = blockIdx.x * 256 + threadIdx.x;
  int rank = 0;
#pragma unroll
  for (int g = 0; g < SEG; g++) rank += partial[((size_t)hh * SEG + g) * NNODE + mi];
  float mk = s[(size_t)hh * NNODE + mi];
  ss[(size_t)hh * NNODE + rank] = mk;
  si[(size_t)hh * NNODE + rank] = mi;
}

// Pass A: per-chunk partial sums of e^{s}*h (P) and e^{0.2s}*h (M); z at col 128.
// ids/exps staged in LDS; h gathered in unroll-8 register batches (pipelined).
__global__ __launch_bounds__(128) void passA_kernel(const float* __restrict__ h,
                                                    const float* __restrict__ ss,
                                                    const int* __restrict__ si,
                                                    float* __restrict__ partP,
                                                    float* __restrict__ partM, int H) {
  __shared__ float eP[CHUNK], eM[CHUNK];
  __shared__ int ids[CHUNK];
  int b = blockIdx.x, hh = b / NCHUNK, ci = b % NCHUNK;
  int c = threadIdx.x;
  int HC = H * CDIM;
  int base = ci * CHUNK;
  if (c < CHUNK) {
    float sv = ss[(size_t)hh * NNODE + base + c];
    ids[c] = si[(size_t)hh * NNODE + base + c];
    eP[c] = expf(sv);
    eM[c] = expf(NEG * sv);
  }
  __syncthreads();
  float sp = 0.f, sm = 0.f;
  for (int kb = 0; kb < CHUNK; kb += 8) {
    float v[8];
#pragma unroll
    for (int j = 0; j < 8; j++)
      v[j] = h[(size_t)ids[kb + j] * HC + hh * CDIM + c];
#pragma unroll
    for (int j = 0; j < 8; j++) {
      sp = fmaf(eP[kb + j], v[j], sp);
      sm = fmaf(eM[kb + j], v[j], sm);
    }
  }
  size_t o = ((size_t)hh * NCHUNK + ci) * TW;
  partP[o + c] = sp;
  partM[o + c] = sm;
  if (c == 0) {
    float zp = 0.f, zm = 0.f;
#pragma unroll
    for (int k = 0; k < CHUNK; k++) { zp += eP[k]; zm += eM[k]; }
    partP[o + 128] = zp;
    partM[o + 128] = zm;
  }
}

// Pass B: chunk carries. One block per head, thread c handles column c
// (c==128 -> z). All 64 partials loaded into registers (in flight), then
// register prefix (M) / suffix (P) scans.
__global__ __launch_bounds__(192) void passB_kernel(const float* __restrict__ partP,
                                                    const float* __restrict__ partM,
                                                    float* __restrict__ carryP,
                                                    float* __restrict__ carryM) {
  int hh = blockIdx.x, c = threadIdx.x;
  if (c > 128) return;
  float vM[NCHUNK], vP[NCHUNK];
#pragma unroll
  for (int g = 0; g < NCHUNK; g++) {
    size_t o = ((size_t)hh * NCHUNK + g) * TW + c;
    vM[g] = partM[o];
    vP[g] = partP[o];
  }
  float run = 0.f;
#pragma unroll
  for (int g = 0; g < NCHUNK; g++) {
    carryM[((size_t)hh * NCHUNK + g) * TW + c] = run;
    run += vM[g];
  }
  run = 0.f;
#pragma unroll
  for (int g = NCHUNK - 1; g >= 0; g--) {
    carryP[((size_t)hh * NCHUNK + g) * TW + c] = run;
    run += vP[g];
  }
}

// Pass C: full tables, z at col 128. Gather h once into LDS scratch
// (per-thread column, batched global loads), then scan twice from LDS.
__global__ __launch_bounds__(128) void passC_kernel(const float* __restrict__ h,
                                                    const float* __restrict__ ss,
                                                    const int* __restrict__ si,
                                                    const float* __restrict__ carryP,
                                                    const float* __restrict__ carryM,
                                                    float* __restrict__ SS,
                                                    float* __restrict__ PP, int H) {
  __shared__ float hrow[CHUNK][CDIM];  // 32 KB; hrow[k][c] touched only by thread c
  __shared__ float eP[CHUNK], eM[CHUNK];
  __shared__ int ids[CHUNK];
  int b = blockIdx.x, hh = b / NCHUNK, ci = b % NCHUNK;
  int c = threadIdx.x;
  int HC = H * CDIM;
  int base = ci * CHUNK;
  size_t hb = (size_t)hh * (NNODE + 1);
  if (c < CHUNK) {
    float sv = ss[(size_t)hh * NNODE + base + c];
    ids[c] = si[(size_t)hh * NNODE + base + c];
    eP[c] = expf(sv);
    eM[c] = expf(NEG * sv);
  }
  __syncthreads();
  for (int kb = 0; kb < CHUNK; kb += 8) {
    float v[8];
#pragma unroll
    for (int j = 0; j < 8; j++)
      v[j] = h[(size_t)ids[kb + j] * HC + hh * CDIM + c];
#pragma unroll
    for (int j = 0; j < 8; j++) hrow[kb + j][c] = v[j];
  }
  // no sync needed: hrow[k][c] written and read by the same thread
  size_t co = ((size_t)hh * NCHUNK + ci) * TW;
  float runm = carryM[co + c], runzm = carryM[co + 128];
#pragma unroll 8
  for (int k = 0; k < CHUNK; k++) {
    size_t row = (hb + base + k) * TW;
    PP[row + c] = runm;
    if (c == 0) PP[row + 128] = runzm;
    runm = fmaf(eM[k], hrow[k][c], runm);
    runzm += eM[k];
  }
  if (ci == NCHUNK - 1) {
    size_t row = (hb + NNODE) * TW;
    PP[row + c] = runm;
    if (c == 0) PP[row + 128] = runzm;
  }
  float runp = carryP[co + c], runzp = carryP[co + 128];
#pragma unroll 8
  for (int k = CHUNK - 1; k >= 0; k--) {
    runp = fmaf(eP[k], hrow[k][c], runp);
    runzp += eP[k];
    size_t row = (hb + base + k) * TW;
    SS[row + c] = runp;
    if (c == 0) SS[row + 128] = runzp;
  }
  if (ci == NCHUNK - 1) {
    size_t row = (hb + NNODE) * TW;
    SS[row + c] = 0.f;
    if (c == 0) SS[row + 128] = 0.f;
  }
}

// Per (dest, head): binary search split point, combine tables, +bias, ELU.
// OUT = unsigned short (bf16, feeds MFMA GEMM2) or float.
template <typename OUT>
__global__ __launch_bounds__(128) void attend_kernel(const float* __restrict__ SS,
                                                     const float* __restrict__ PP,
                                                     const float* __restrict__ ss,
                                                     const float* __restrict__ tt,
                                                     const float* __restrict__ bias,
                                                     OUT* __restrict__ out, int H) {
  int b = blockIdx.x;
  int n = b / H, hh = b % H;
  int c = threadIdx.x;
  float tv = tt[(size_t)hh * NNODE + n];
  const float* sp = ss + (size_t)hh * NNODE;
  float thr = -tv;
  int lo = 0, hi = NNODE;
  while (lo < hi) { int mid = (lo + hi) >> 1; if (sp[mid] < thr) lo = mid + 1; else hi = mid; }
  size_t hb = (size_t)hh * (NNODE + 1);
  float wp = expf(tv), wm = expf(NEG * tv);
  float num = wp * SS[(hb + lo) * TW + c] + wm * PP[(hb + lo) * TW + c];
  float Z = wp * SS[(hb + lo) * TW + 128] + wm * PP[(hb + lo) * TW + 128];
  float o = num / Z + bias[hh * CDIM + c];
  float r = (o > 0.f) ? o : (expf(o) - 1.f);
  if constexpr (sizeof(OUT) == 2)
    out[(size_t)n * (H * CDIM) + hh * CDIM + c] = f2b(r);
  else
    out[(size_t)n * (H * CDIM) + hh * CDIM + c] = r;
}

__global__ __launch_bounds__(256) void mean_kernel(const float* __restrict__ x,
                                                   float* __restrict__ m) {
  __shared__ float red[256];
  int c = blockIdx.x, tid = threadIdx.x;
  float acc = 0.f;
  for (int i = tid; i < NNODE; i += 256) acc += x[(size_t)i * CDIM + c];
  red[tid] = acc; __syncthreads();
  for (int o = 128; o > 0; o >>= 1) { if (tid < o) red[tid] += red[tid + o]; __syncthreads(); }
  if (tid == 0) m[c] = red[0] * (1.f / NNODE);
}

__global__ __launch_bounds__(256) void fc_kernel(const float* __restrict__ m,
                                                 const float* __restrict__ fcW,
                                                 const float* __restrict__ fcb,
                                                 float* __restrict__ out) {
  int d = blockIdx.x * 256 + threadIdx.x;  // 768 total
  float acc = fcb[d];
  for (int c2 = 0; c2 < CDIM; c2++) acc = fmaf(m[c2], fcW[c2 * 768 + d], acc);
  out[d] = acc;
}

extern "C" void kernel_launch(void* const* d_in, const int* in_sizes, int n_in,
                              void* d_out, int out_size, void* d_ws, size_t ws_size,
                              hipStream_t stream) {
  const float* x   = (const float*)d_in[0];
  const float* W1  = (const float*)d_in[1];
  const float* as1 = (const float*)d_in[2];
  const float* ad1 = (const float*)d_in[3];
  const float* b1  = (const float*)d_in[4];
  const float* W2  = (const float*)d_in[5];
  const float* as2 = (const float*)d_in[6];
  const float* ad2 = (const float*)d_in[7];
  const float* b2  = (const float*)d_in[8];
  const float* fcW = (const float*)d_in[9];
  const float* fcb = (const float*)d_in[10];

  float* ws = (float*)d_ws;
  size_t off = 0;
  auto alloc = [&](size_t nfloats) { float* p = ws + off; off += nfloats; return p; };

  float* h1  = alloc((size_t)NNODE * 512);
  float* x2f = alloc((size_t)NNODE * 512);   // first half: x2b bf16; tail: W2t
  float* h2  = alloc((size_t)NNODE * 128);
  float* x3  = alloc((size_t)NNODE * 128);
  float* s1  = alloc((size_t)4 * NNODE);
  float* t1  = alloc((size_t)4 * NNODE);
  float* sS1 = alloc((size_t)4 * NNODE);
  int*   sI1 = (int*)alloc((size_t)4 * NNODE);
  float* SS1 = alloc((size_t)4 * (NNODE + 1) * TW);
  float* PP1 = alloc((size_t)4 * (NNODE + 1) * TW);
  float* pP1 = alloc((size_t)4 * NCHUNK * TW);
  float* pM1 = alloc((size_t)4 * NCHUNK * TW);
  float* cP1 = alloc((size_t)4 * NCHUNK * TW);
  float* cM1 = alloc((size_t)4 * NCHUNK * TW);
  float* s2  = alloc(NNODE);
  float* t2  = alloc(NNODE);
  float* sS2 = alloc(NNODE);
  int*   sI2 = (int*)alloc(NNODE);
  float* SS2 = alloc((size_t)(NNODE + 1) * TW);
  float* PP2 = alloc((size_t)(NNODE + 1) * TW);
  float* pP2 = alloc((size_t)NCHUNK * TW);
  float* pM2 = alloc((size_t)NCHUNK * TW);
  float* cP2 = alloc((size_t)NCHUNK * TW);
  float* cM2 = alloc((size_t)NCHUNK * TW);
  float* mv  = alloc(128);
  int*   rparts = (int*)alloc((size_t)4 * SEG * NNODE);

  // bf16 staging aliased into PP1/SS1 (first written by passC1, strictly after
  // gemm1 last reads them — stream ordered).
  unsigned short* xb  = (unsigned short*)PP1;  // 4096x768 bf16 = 6.3 MB (< 8.65 MB)
  unsigned short* W1t = (unsigned short*)SS1;  // 512x768 bf16
  unsigned short* x2b = (unsigned short*)x2f;                       // 4096x512 bf16
  unsigned short* W2t = (unsigned short*)(x2f + NNODE * 256 + 64);  // 128x512 bf16

  // Prep: convert x + transpose/cast W1, W2 (one kernel)
  prep_kernel<<<3072 + 96 + 16, 256, 0, stream>>>(x, W1, W2, xb, W1t, W2t);
  // Layer 1  (64x64 tiles -> 512 blocks, 2 blocks/CU)
  mfma_gemm_bt<64, 64><<<dim3(512 / 64, NNODE / 64), 256, 0, stream>>>(xb, W1t, h1, NNODE, 512, 768);
  st_kernel<<<NNODE, 4 * 64, 0, stream>>>(h1, as1, ad1, s1, t1, 4);
  rank_count_kernel<<<dim3(NNODE / 256, SEG, 4), 256, 0, stream>>>(s1, rparts);
  rank_scatter_kernel<<<dim3(NNODE / 256, 4), 256, 0, stream>>>(s1, rparts, sS1, sI1);
  passA_kernel<<<4 * NCHUNK, 128, 0, stream>>>(h1, sS1, sI1, pP1, pM1, 4);
  passB_kernel<<<4, 192, 0, stream>>>(pP1, pM1, cP1, cM1);
  passC_kernel<<<4 * NCHUNK, 128, 0, stream>>>(h1, sS1, sI1, cP1, cM1, SS1, PP1, 4);
  attend_kernel<unsigned short><<<NNODE * 4, 128, 0, stream>>>(SS1, PP1, sS1, t1, b1, x2b, 4);
  // Layer 2  (32x64 tiles -> 256 blocks)
  mfma_gemm_bt<32, 64><<<dim3(128 / 64, NNODE / 32), 256, 0, stream>>>(x2b, W2t, h2, NNODE, 128, 512);
  st_kernel<<<NNODE, 1 * 64, 0, stream>>>(h2, as2, ad2, s2, t2, 1);
  rank_count_kernel<<<dim3(NNODE / 256, SEG, 1), 256, 0, stream>>>(s2, rparts);
  rank_scatter_kernel<<<dim3(NNODE / 256, 1), 256, 0, stream>>>(s2, rparts, sS2, sI2);
  passA_kernel<<<NCHUNK, 128, 0, stream>>>(h2, sS2, sI2, pP2, pM2, 1);
  passB_kernel<<<1, 192, 0, stream>>>(pP2, pM2, cP2, cM2);
  passC_kernel<<<NCHUNK, 128, 0, stream>>>(h2, sS2, sI2, cP2, cM2, SS2, PP2, 1);
  attend_kernel<float><<<NNODE, 128, 0, stream>>>(SS2, PP2, sS2, t2, b2, x3, 1);
  // Readout
  mean_kernel<<<128, 256, 0, stream>>>(x3, mv);
  fc_kernel<<<3, 256, 0, stream>>>(mv, fcW, fcb, (float*)d_out);
}